// Round 1
// baseline (902.706 us; speedup 1.0000x reference)
//
#include <hip/hip_runtime.h>
#include <hip/hip_bf16.h>
#include <math.h>

// ---------------- problem constants (fixed by setup_inputs) ----------------
#define P_N   300          // proposals
#define C_N   512          // channels
#define H_F   50           // feat H  (800/16)
#define W_F   67           // feat W  (1072/16)
#define HW_F  (H_F * W_F)  // 3350
#define D_N   1024         // fc width
#define FIN   25088        // 512*7*7
#define NCLS  21
#define NCAND 6000         // 300*20
#define SORT_N 8192
#define W_IMG 1072.0f
#define H_IMG 800.0f
#define BBOX_CLIP_F 4.135166556742356f
#define KS6   8            // K-splits for fc6
#define KS7   2            // K-splits for fc7

// ---------------- feat (C,H,W) -> (H*W, C) transpose ----------------
__global__ __launch_bounds__(256) void transpose_feat(const float* __restrict__ feat,
                                                      float* __restrict__ ft) {
  __shared__ float tile[32][33];
  const int s0 = blockIdx.x * 32;   // spatial
  const int c0 = blockIdx.y * 32;   // channel
  const int tx = threadIdx.x, ty = threadIdx.y; // 32 x 8
  for (int r = ty; r < 32; r += 8) {
    int c = c0 + r, s = s0 + tx;
    tile[r][tx] = (s < HW_F) ? feat[(size_t)c * HW_F + s] : 0.0f;
  }
  __syncthreads();
  for (int r = ty; r < 32; r += 8) {
    int s = s0 + r, c = c0 + tx;
    if (s < HW_F) ft[(size_t)s * C_N + c] = tile[tx][r];
  }
}

// ---------------- ROI align: block per (proposal, cell); 512 ch over 256 lanes ----------------
__global__ __launch_bounds__(256) void roi_align_k(const float* __restrict__ ft,
                                                   const float* __restrict__ rois,
                                                   float* __restrict__ X) {
  const int p = blockIdx.x;
  const int cell = blockIdx.y;          // 0..48
  const int py = cell / 7, px = cell % 7;
  const float rx0 = rois[p*4+0], ry0 = rois[p*4+1], rx1 = rois[p*4+2], ry1 = rois[p*4+3];
  const float x0r = rx0 * 0.0625f - 0.5f;
  const float y0r = ry0 * 0.0625f - 0.5f;
  const float bw  = (rx1 - rx0) * 0.0625f * (1.0f / 7.0f);
  const float bh  = (ry1 - ry0) * 0.0625f * (1.0f / 7.0f);

  int   yl[2], yh[2], xl[2], xh[2];
  float ly[2], hy[2], lx[2], hx[2];
  bool  vy[2], vx[2];
#pragma unroll
  for (int s = 0; s < 2; ++s) {
    float t  = ((float)(2*py + s) + 0.5f) * 0.5f;
    float ys = y0r + bh * t;
    vy[s] = (ys >= -1.0f) && (ys <= (float)H_F);
    float y = fminf(fmaxf(ys, 0.0f), (float)(H_F - 1));
    int yi = (int)floorf(y);
    yl[s] = yi; yh[s] = min(yi + 1, H_F - 1);
    ly[s] = y - (float)yi; hy[s] = 1.0f - ly[s];

    float t2 = ((float)(2*px + s) + 0.5f) * 0.5f;
    float xs = x0r + bw * t2;
    vx[s] = (xs >= -1.0f) && (xs <= (float)W_F);
    float x = fminf(fmaxf(xs, 0.0f), (float)(W_F - 1));
    int xi = (int)floorf(x);
    xl[s] = xi; xh[s] = min(xi + 1, W_F - 1);
    lx[s] = x - (float)xi; hx[s] = 1.0f - lx[s];
  }

  const int c = threadIdx.x;
  float acc0 = 0.0f, acc1 = 0.0f;
#pragma unroll
  for (int sy = 0; sy < 2; ++sy) {
#pragma unroll
    for (int sx = 0; sx < 2; ++sx) {
      if (vy[sy] && vx[sx]) {
        const float w00 = hy[sy]*hx[sx], w01 = hy[sy]*lx[sx];
        const float w10 = ly[sy]*hx[sx], w11 = ly[sy]*lx[sx];
        const float* p00 = ft + (size_t)(yl[sy]*W_F + xl[sx]) * C_N;
        const float* p01 = ft + (size_t)(yl[sy]*W_F + xh[sx]) * C_N;
        const float* p10 = ft + (size_t)(yh[sy]*W_F + xl[sx]) * C_N;
        const float* p11 = ft + (size_t)(yh[sy]*W_F + xh[sx]) * C_N;
        acc0 += w00*p00[c]     + w01*p01[c]     + w10*p10[c]     + w11*p11[c];
        acc1 += w00*p00[c+256] + w01*p01[c+256] + w10*p10[c+256] + w11*p11[c+256];
      }
    }
  }
  X[(size_t)p*FIN + (size_t)c*49 + cell]       = acc0 * 0.25f;
  X[(size_t)p*FIN + (size_t)(c+256)*49 + cell] = acc1 * 0.25f;
}

// ---------------- f32 tiled GEMM: out[m][n] = sum_k X[m][k]*W[n][k], split-K partials ----------------
#define BM 64
#define BN 64
#define BK 32
__global__ __launch_bounds__(256) void gemm_split(const float* __restrict__ Xm,
                                                  const float* __restrict__ Wm,
                                                  float* __restrict__ Pt,
                                                  int M, int N, int K, int kchunk) {
  __shared__ float As[BK][BM + 4];
  __shared__ float Bs[BK][BN + 4];
  const int tid = threadIdx.x;
  const int tx = tid & 15, ty = tid >> 4;
  const int m0 = blockIdx.x * BM, n0 = blockIdx.y * BN;
  const int k0 = blockIdx.z * kchunk;
  int kend = k0 + kchunk; if (kend > K) kend = K;

  float acc[4][4] = {};
  for (int kb = k0; kb < kend; kb += BK) {
    // stage A (X tile): BM x BK
    for (int li = tid; li < (BM * BK) / 4; li += 256) {
      int row = li >> 3;            // BK/4 = 8 float4 per row
      int col = (li & 7) * 4;
      int gm = m0 + row;
      float4 v = make_float4(0.f, 0.f, 0.f, 0.f);
      if (gm < M) v = *reinterpret_cast<const float4*>(&Xm[(size_t)gm * K + kb + col]);
      As[col+0][row] = v.x; As[col+1][row] = v.y; As[col+2][row] = v.z; As[col+3][row] = v.w;
    }
    // stage B (W tile): BN x BK   (N is always a multiple of BN here)
    for (int li = tid; li < (BN * BK) / 4; li += 256) {
      int row = li >> 3;
      int col = (li & 7) * 4;
      int gn = n0 + row;
      float4 v = *reinterpret_cast<const float4*>(&Wm[(size_t)gn * K + kb + col]);
      Bs[col+0][row] = v.x; Bs[col+1][row] = v.y; Bs[col+2][row] = v.z; Bs[col+3][row] = v.w;
    }
    __syncthreads();
#pragma unroll
    for (int kk = 0; kk < BK; ++kk) {
      const float4 a = *reinterpret_cast<const float4*>(&As[kk][ty * 4]);
      const float4 b = *reinterpret_cast<const float4*>(&Bs[kk][tx * 4]);
      float ar[4] = {a.x, a.y, a.z, a.w};
      float br[4] = {b.x, b.y, b.z, b.w};
#pragma unroll
      for (int i = 0; i < 4; ++i)
#pragma unroll
        for (int j = 0; j < 4; ++j)
          acc[i][j] = fmaf(ar[i], br[j], acc[i][j]);
    }
    __syncthreads();
  }
  float* outp = Pt + (size_t)blockIdx.z * M * N;
#pragma unroll
  for (int i = 0; i < 4; ++i) {
    int m = m0 + ty * 4 + i;
    if (m < M) {
      float4 v = make_float4(acc[i][0], acc[i][1], acc[i][2], acc[i][3]);
      *reinterpret_cast<float4*>(&outp[(size_t)m * N + n0 + tx * 4]) = v;
    }
  }
}

// ---------------- reduce split-K partials + bias + relu ----------------
__global__ __launch_bounds__(256) void reduce_bias_relu(const float* __restrict__ Pt,
                                                        const float* __restrict__ bias,
                                                        float* __restrict__ out,
                                                        int MN, int KS) {
  int i = blockIdx.x * 256 + threadIdx.x;
  if (i >= MN) return;
  float s = 0.0f;
  for (int k = 0; k < KS; ++k) s += Pt[(size_t)k * MN + i];
  s += bias[i & (D_N - 1)];
  out[i] = fmaxf(s, 0.0f);
}

// ---------------- head: cls+reg dots, softmax, decode, clip, validity ----------------
__global__ __launch_bounds__(128) void head_kernel(const float* __restrict__ h7,
                                                   const float* __restrict__ cls_w,
                                                   const float* __restrict__ cls_b,
                                                   const float* __restrict__ reg_w,
                                                   const float* __restrict__ reg_b,
                                                   const float* __restrict__ props,
                                                   float* __restrict__ cboxes,
                                                   float* __restrict__ cscores,
                                                   int* __restrict__ cvalid) {
  const int p = blockIdx.x;
  __shared__ float h[D_N];
  __shared__ float outv[105];   // 21 cls + 84 reg
  __shared__ float sm[NCLS];
  const int tid = threadIdx.x;
  for (int k = tid; k < D_N; k += 128) h[k] = h7[(size_t)p * D_N + k];
  __syncthreads();

  const int wv = tid >> 6, lane = tid & 63;
  for (int o = wv; o < 105; o += 2) {
    const float* wr = (o < NCLS) ? &cls_w[(size_t)o * D_N] : &reg_w[(size_t)(o - NCLS) * D_N];
    float s = 0.0f;
    for (int k = lane; k < D_N; k += 64) s += h[k] * wr[k];
#pragma unroll
    for (int off = 32; off > 0; off >>= 1) s += __shfl_down(s, off);
    if (lane == 0) outv[o] = s + ((o < NCLS) ? cls_b[o] : reg_b[o - NCLS]);
  }
  __syncthreads();

  if (tid == 0) {
    float mx = outv[0];
    for (int c2 = 1; c2 < NCLS; ++c2) mx = fmaxf(mx, outv[c2]);
    float sum = 0.0f;
    for (int c2 = 0; c2 < NCLS; ++c2) { float e = expf(outv[c2] - mx); sm[c2] = e; sum += e; }
    float inv = 1.0f / sum;
    for (int c2 = 0; c2 < NCLS; ++c2) sm[c2] *= inv;
  }
  __syncthreads();

  if (tid < 20) {
    const int c = tid + 1;
    const float x0 = props[p*4+0], y0 = props[p*4+1], x1 = props[p*4+2], y1 = props[p*4+3];
    const float w = x1 - x0, hh = y1 - y0;
    const float cx = x0 + 0.5f * w, cy = y0 + 0.5f * hh;
    const float dx = outv[NCLS + c*4 + 0];
    const float dy = outv[NCLS + c*4 + 1];
    const float dw = fminf(outv[NCLS + c*4 + 2], BBOX_CLIP_F);
    const float dh = fminf(outv[NCLS + c*4 + 3], BBOX_CLIP_F);
    const float pcx = dx * w + cx, pcy = dy * hh + cy;
    const float pw = expf(dw) * w, ph = expf(dh) * hh;
    float bx0 = pcx - 0.5f * pw, by0 = pcy - 0.5f * ph;
    float bx1 = pcx + 0.5f * pw, by1 = pcy + 0.5f * ph;
    bx0 = fminf(fmaxf(bx0, 0.0f), W_IMG);
    by0 = fminf(fmaxf(by0, 0.0f), H_IMG);
    bx1 = fminf(fmaxf(bx1, 0.0f), W_IMG);
    by1 = fminf(fmaxf(by1, 0.0f), H_IMG);
    const int idx = p * 20 + tid;
    cboxes[idx*4+0] = bx0; cboxes[idx*4+1] = by0;
    cboxes[idx*4+2] = bx1; cboxes[idx*4+3] = by1;
    const float sc = sm[c];
    const bool valid = (sc > 0.05f) && ((bx1 - bx0) >= 1.0f) && ((by1 - by0) >= 1.0f);
    cscores[idx] = sc;
    cvalid[idx] = valid ? 1 : 0;
  }
}

// ---------------- bitonic sort of 8192 u64 keys (desc score, asc idx) ----------------
__global__ __launch_bounds__(1024) void sort_kernel(const float* __restrict__ cscores,
                                                    const int* __restrict__ cvalid,
                                                    unsigned long long* __restrict__ skeys) {
  __shared__ unsigned long long keys[SORT_N];
  const int tid = threadIdx.x;
  for (int i = tid; i < SORT_N; i += 1024) {
    unsigned long long k;
    if (i < NCAND) {
      float s = cvalid[i] ? cscores[i] : -__builtin_inff();
      unsigned u = __float_as_uint(s);
      u = (u & 0x80000000u) ? ~u : (u | 0x80000000u);   // ascending-sortable
      unsigned d = ~u;                                   // descending
      k = ((unsigned long long)d << 32) | (unsigned)i;
    } else {
      k = ~0ULL;
    }
    keys[i] = k;
  }
  __syncthreads();
  for (int kk = 2; kk <= SORT_N; kk <<= 1) {
    for (int j = kk >> 1; j > 0; j >>= 1) {
      for (int i = tid; i < SORT_N; i += 1024) {
        int ij = i ^ j;
        if (ij > i) {
          unsigned long long a = keys[i], b = keys[ij];
          bool up = ((i & kk) == 0);
          if ((a > b) == up) { keys[i] = b; keys[ij] = a; }
        }
      }
      __syncthreads();
    }
  }
  for (int i = tid; i < SORT_N; i += 1024) skeys[i] = keys[i];
}

// ---------------- greedy NMS (single wave) + final output ----------------
__global__ __launch_bounds__(64) void nms_kernel(const unsigned long long* __restrict__ skeys,
                                                 const float* __restrict__ cboxes,
                                                 float* __restrict__ out) {
  __shared__ float kb[100][4];
  __shared__ int   kl[100];
  const int lane = threadIdx.x;
  int nk = 0;
  for (int i = 0; i < NCAND; ++i) {
    if (nk >= 100) break;
    const unsigned long long key = skeys[i];
    const unsigned d = (unsigned)(key >> 32);
    const unsigned u = ~d;
    const unsigned bits = (u & 0x80000000u) ? (u ^ 0x80000000u) : ~u;
    const float s = __uint_as_float(bits);
    if (!(s > 0.0f)) break;                 // -inf (invalid) or padding: stop
    const int idx = (int)(key & 0xffffffffu);
    const float bx0 = cboxes[idx*4+0], by0 = cboxes[idx*4+1];
    const float bx1 = cboxes[idx*4+2], by1 = cboxes[idx*4+3];
    const int lab = idx % 20;
    const float area_i = (bx1 - bx0) * (by1 - by0);

    bool sup = false;
    for (int j = lane; j < nk; j += 64) {
      if (kl[j] == lab) {
        const float kx0 = kb[j][0], ky0 = kb[j][1], kx1 = kb[j][2], ky1 = kb[j][3];
        const float iw = fminf(kx1, bx1) - fmaxf(kx0, bx0);
        const float ih = fminf(ky1, by1) - fmaxf(ky0, by0);
        const float inter = fmaxf(iw, 0.0f) * fmaxf(ih, 0.0f);
        const float area_j = (kx1 - kx0) * (ky1 - ky0);
        const float iou = inter / (area_i + area_j - inter);
        if (iou > 0.5f) sup = true;
      }
    }
    const bool any = (__any(sup) != 0);
    if (!any) {
      if (lane == 0) {
        kb[nk][0] = bx0; kb[nk][1] = by0; kb[nk][2] = bx1; kb[nk][3] = by1;
        kl[nk] = lab;
        out[nk*4+0] = bx0; out[nk*4+1] = by0; out[nk*4+2] = bx1; out[nk*4+3] = by1;
        out[400 + nk] = (float)lab;
        out[500 + nk] = s;
      }
      nk++;
    }
    __syncthreads();
  }
  for (int r = nk + lane; r < 100; r += 64) {
    out[r*4+0] = 0.0f; out[r*4+1] = 0.0f; out[r*4+2] = 0.0f; out[r*4+3] = 0.0f;
    out[400 + r] = -1.0f;
    out[500 + r] = 0.0f;
  }
}

// ---------------- launch ----------------
extern "C" void kernel_launch(void* const* d_in, const int* in_sizes, int n_in,
                              void* d_out, int out_size, void* d_ws, size_t ws_size,
                              hipStream_t stream) {
  const float* feat   = (const float*)d_in[1];
  const float* props  = (const float*)d_in[2];
  const float* fc6_w  = (const float*)d_in[3];
  const float* fc6_b  = (const float*)d_in[4];
  const float* fc7_w  = (const float*)d_in[5];
  const float* fc7_b  = (const float*)d_in[6];
  const float* cls_w  = (const float*)d_in[7];
  const float* cls_b  = (const float*)d_in[8];
  const float* reg_w  = (const float*)d_in[9];
  const float* reg_b  = (const float*)d_in[10];

  char* ws = (char*)d_ws;
  size_t off = 0;
  auto alloc = [&](size_t bytes) -> void* {
    void* p = ws + off;
    off += (bytes + 255) & ~(size_t)255;
    return p;
  };

  float* ft      = (float*)alloc((size_t)HW_F * C_N * 4);              // 6.9 MB
  float* X       = (float*)alloc((size_t)P_N * FIN * 4);               // 30.1 MB
  float* Pt      = (float*)alloc((size_t)KS6 * P_N * D_N * 4);         // 9.8 MB
  float* h6      = (float*)alloc((size_t)P_N * D_N * 4);               // 1.2 MB
  float* h7      = (float*)alloc((size_t)P_N * D_N * 4);               // 1.2 MB
  float* cboxes  = (float*)alloc((size_t)NCAND * 4 * 4);
  float* cscores = (float*)alloc((size_t)NCAND * 4);
  int*   cvalid  = (int*)alloc((size_t)NCAND * 4);
  unsigned long long* skeys = (unsigned long long*)alloc((size_t)SORT_N * 8);
  (void)ws_size; (void)in_sizes; (void)n_in; (void)out_size;

  // 1) feat (C,HW) -> (HW,C)
  transpose_feat<<<dim3((HW_F + 31) / 32, C_N / 32), dim3(32, 8), 0, stream>>>(feat, ft);
  // 2) ROI align -> X [300][25088]
  roi_align_k<<<dim3(P_N, 49), 256, 0, stream>>>(ft, props, X);
  // 3) fc6
  gemm_split<<<dim3((P_N + BM - 1) / BM, D_N / BN, KS6), 256, 0, stream>>>(
      X, fc6_w, Pt, P_N, D_N, FIN, FIN / KS6);
  reduce_bias_relu<<<(P_N * D_N + 255) / 256, 256, 0, stream>>>(Pt, fc6_b, h6, P_N * D_N, KS6);
  // 4) fc7
  gemm_split<<<dim3((P_N + BM - 1) / BM, D_N / BN, KS7), 256, 0, stream>>>(
      h6, fc7_w, Pt, P_N, D_N, D_N, D_N / KS7);
  reduce_bias_relu<<<(P_N * D_N + 255) / 256, 256, 0, stream>>>(Pt, fc7_b, h7, P_N * D_N, KS7);
  // 5) heads + softmax + decode
  head_kernel<<<P_N, 128, 0, stream>>>(h7, cls_w, cls_b, reg_w, reg_b, props,
                                       cboxes, cscores, cvalid);
  // 6) sort candidates
  sort_kernel<<<1, 1024, 0, stream>>>(cscores, cvalid, skeys);
  // 7) NMS + write output (600 floats: 400 boxes, 100 labels, 100 scores)
  nms_kernel<<<1, 64, 0, stream>>>(skeys, cboxes, (float*)d_out);
}

// Round 2
// 666.868 us; speedup vs baseline: 1.3536x; 1.3536x over previous
//
#include <hip/hip_runtime.h>
#include <hip/hip_bf16.h>
#include <math.h>

// ---------------- problem constants ----------------
#define P_N   300
#define C_N   512
#define H_F   50
#define W_F   67
#define HW_F  3350
#define D_N   1024
#define FIN   25088
#define NCLS  21
#define NCAND 6000
#define W_IMG 1072.0f
#define H_IMG 800.0f
#define BBOX_CLIP_F 4.135166556742356f
#define KS6   21
#define STEPS6_PER_Z 38
#define KS7   4
#define STEPS7_PER_Z 8
#define LO_SCALE 2048.0f
#define LO_INV   (1.0f/2048.0f)

typedef __attribute__((ext_vector_type(8)))  _Float16 half8;
typedef __attribute__((ext_vector_type(16))) float    f32x16;

__device__ __forceinline__ void split16(float f, _Float16& h, _Float16& l) {
  h = (_Float16)f;
  l = (_Float16)((f - (float)h) * LO_SCALE);
}

// ---------------- feat (C,H,W) -> (H*W, C) transpose ----------------
__global__ __launch_bounds__(256) void transpose_feat(const float* __restrict__ feat,
                                                      float* __restrict__ ft) {
  __shared__ float tile[32][33];
  const int s0 = blockIdx.x * 32, c0 = blockIdx.y * 32;
  const int tx = threadIdx.x, ty = threadIdx.y;
  for (int r = ty; r < 32; r += 8) {
    int c = c0 + r, s = s0 + tx;
    tile[r][tx] = (s < HW_F) ? feat[(size_t)c * HW_F + s] : 0.0f;
  }
  __syncthreads();
  for (int r = ty; r < 32; r += 8) {
    int s = s0 + r, c = c0 + tx;
    if (s < HW_F) ft[(size_t)s * C_N + c] = tile[tx][r];
  }
}

// ---------------- ROI align -> X as f16 hi/lo, layout [p][c*49+cell] ----------------
__global__ __launch_bounds__(256) void roi_align_k(const float* __restrict__ ft,
                                                   const float* __restrict__ rois,
                                                   _Float16* __restrict__ Xhi,
                                                   _Float16* __restrict__ Xlo) {
  const int p = blockIdx.x;
  const int cell = blockIdx.y;
  const int py = cell / 7, px = cell % 7;
  const float rx0 = rois[p*4+0], ry0 = rois[p*4+1], rx1 = rois[p*4+2], ry1 = rois[p*4+3];
  const float x0r = rx0 * 0.0625f - 0.5f;
  const float y0r = ry0 * 0.0625f - 0.5f;
  const float bw  = (rx1 - rx0) * 0.0625f * (1.0f / 7.0f);
  const float bh  = (ry1 - ry0) * 0.0625f * (1.0f / 7.0f);

  int   yl[2], yh[2], xl[2], xh[2];
  float ly[2], hy[2], lx[2], hx[2];
  bool  vy[2], vx[2];
#pragma unroll
  for (int s = 0; s < 2; ++s) {
    float t  = ((float)(2*py + s) + 0.5f) * 0.5f;
    float ys = y0r + bh * t;
    vy[s] = (ys >= -1.0f) && (ys <= (float)H_F);
    float y = fminf(fmaxf(ys, 0.0f), (float)(H_F - 1));
    int yi = (int)floorf(y);
    yl[s] = yi; yh[s] = min(yi + 1, H_F - 1);
    ly[s] = y - (float)yi; hy[s] = 1.0f - ly[s];

    float t2 = ((float)(2*px + s) + 0.5f) * 0.5f;
    float xs = x0r + bw * t2;
    vx[s] = (xs >= -1.0f) && (xs <= (float)W_F);
    float x = fminf(fmaxf(xs, 0.0f), (float)(W_F - 1));
    int xi = (int)floorf(x);
    xl[s] = xi; xh[s] = min(xi + 1, W_F - 1);
    lx[s] = x - (float)xi; hx[s] = 1.0f - lx[s];
  }

  const int c = threadIdx.x;
  float acc0 = 0.0f, acc1 = 0.0f;
#pragma unroll
  for (int sy = 0; sy < 2; ++sy) {
#pragma unroll
    for (int sx = 0; sx < 2; ++sx) {
      if (vy[sy] && vx[sx]) {
        const float w00 = hy[sy]*hx[sx], w01 = hy[sy]*lx[sx];
        const float w10 = ly[sy]*hx[sx], w11 = ly[sy]*lx[sx];
        const float* p00 = ft + (size_t)(yl[sy]*W_F + xl[sx]) * C_N;
        const float* p01 = ft + (size_t)(yl[sy]*W_F + xh[sx]) * C_N;
        const float* p10 = ft + (size_t)(yh[sy]*W_F + xl[sx]) * C_N;
        const float* p11 = ft + (size_t)(yh[sy]*W_F + xh[sx]) * C_N;
        acc0 += w00*p00[c]     + w01*p01[c]     + w10*p10[c]     + w11*p11[c];
        acc1 += w00*p00[c+256] + w01*p01[c+256] + w10*p10[c+256] + w11*p11[c+256];
      }
    }
  }
  float v0 = acc0 * 0.25f, v1 = acc1 * 0.25f;
  _Float16 h, l;
  size_t i0 = (size_t)p*FIN + (size_t)c*49 + cell;
  size_t i1 = (size_t)p*FIN + (size_t)(c+256)*49 + cell;
  split16(v0, h, l); Xhi[i0] = h; Xlo[i0] = l;
  split16(v1, h, l); Xhi[i1] = h; Xlo[i1] = l;
}

// ---------------- MFMA f16 3-pass split-K GEMM: out = A(M,K) * W(N=1024,K)^T ----------------
// A pre-split into hi/lo f16; W converted f32->hi/lo in staging.
// LDS fragment order: per (comp, frag16, ks) a 1KB block of 64 lanes x 16B,
// lane l holds elem [row=l&31][k=(l>>5)*8+j] (A) / [col=l&31][k...] (B).
__device__ __forceinline__ int swz(int slot, int ks) {
  return slot ^ ((slot >> 5) & 1) ^ (((slot >> 3) & 1) << 1) ^ ((ks & 1) << 2);
}

__global__ __launch_bounds__(256, 2) void gemm_f16_3p(
    const _Float16* __restrict__ Ahi, const _Float16* __restrict__ Alo,
    const float* __restrict__ Wt, float* __restrict__ Pt,
    int M, int K, int steps_per_z)
{
  __shared__ _Float16 lds[16384];  // 32KB: A hi[0..4095] lo[4096..8191], B hi[8192..] lo[12288..]
  const int tid  = threadIdx.x;
  const int lane = tid & 63, wave = tid >> 6;
  const int wm = wave >> 1, wn = wave & 1;
  const int m0 = blockIdx.x * 128, n0 = blockIdx.y * 128;
  const int steps_total = K >> 5;
  const int s0 = blockIdx.z * steps_per_z;
  const int s1 = min(s0 + steps_per_z, steps_total);

  f32x16 acc0[2][2], acc1[2][2];
#pragma unroll
  for (int a = 0; a < 2; ++a)
#pragma unroll
    for (int b = 0; b < 2; ++b) {
#pragma unroll
      for (int r = 0; r < 16; ++r) { acc0[a][b][r] = 0.f; acc1[a][b][r] = 0.f; }
    }

  const int srow = tid >> 2;           // 0..63
  const int j8   = tid & 3;            // which 8-k chunk of the 32-k step
  const int ksW  = j8 >> 1, kc8 = j8 & 1;
  const int wslot = swz((kc8 << 5) | (srow & 31), ksW);

  for (int step = s0; step < s1; ++step) {
    const int kb = step << 5;
    // ---- stage A (pre-split f16) ----
#pragma unroll
    for (int half = 0; half < 2; ++half) {
      const int row = srow + half * 64;
      const int mf  = row >> 5;
      const int gm  = m0 + row;
      uint4 vh = make_uint4(0,0,0,0), vl = make_uint4(0,0,0,0);
      if (gm < M) {
        vh = *reinterpret_cast<const uint4*>(Ahi + (size_t)gm * K + kb + j8 * 8);
        vl = *reinterpret_cast<const uint4*>(Alo + (size_t)gm * K + kb + j8 * 8);
      }
      const int base = (mf * 2 + ksW) * 512 + wslot * 8;
      *reinterpret_cast<uint4*>(&lds[base])        = vh;
      *reinterpret_cast<uint4*>(&lds[4096 + base]) = vl;
    }
    // ---- stage B (convert f32 W -> f16 hi/lo) ----
#pragma unroll
    for (int half = 0; half < 2; ++half) {
      const int n = srow + half * 64;
      const float* wp = Wt + (size_t)(n0 + n) * K + kb + j8 * 8;
      const float4 f0 = *reinterpret_cast<const float4*>(wp);
      const float4 f1 = *reinterpret_cast<const float4*>(wp + 4);
      float fv[8] = {f0.x, f0.y, f0.z, f0.w, f1.x, f1.y, f1.z, f1.w};
      union { _Float16 h[8]; uint4 v; } uh, ul;
#pragma unroll
      for (int e = 0; e < 8; ++e) split16(fv[e], uh.h[e], ul.h[e]);
      const int nf = n >> 5;
      const int base = 8192 + (nf * 2 + ksW) * 512 + wslot * 8;
      *reinterpret_cast<uint4*>(&lds[base])        = uh.v;
      *reinterpret_cast<uint4*>(&lds[4096 + base]) = ul.v;
    }
    __syncthreads();
    // ---- compute: 2 k-halves x 2x2 frags x 3 passes ----
#pragma unroll
    for (int ks = 0; ks < 2; ++ks) {
      const int rslot = swz(lane, ks) * 8;
      half8 ah[2], al[2], bh[2], bl[2];
#pragma unroll
      for (int mi = 0; mi < 2; ++mi) {
        const int mf = wm * 2 + mi;
        ah[mi] = *reinterpret_cast<const half8*>(&lds[(mf * 2 + ks) * 512 + rslot]);
        al[mi] = *reinterpret_cast<const half8*>(&lds[4096 + (mf * 2 + ks) * 512 + rslot]);
      }
#pragma unroll
      for (int ni = 0; ni < 2; ++ni) {
        const int nf = wn * 2 + ni;
        bh[ni] = *reinterpret_cast<const half8*>(&lds[8192  + (nf * 2 + ks) * 512 + rslot]);
        bl[ni] = *reinterpret_cast<const half8*>(&lds[12288 + (nf * 2 + ks) * 512 + rslot]);
      }
#pragma unroll
      for (int mi = 0; mi < 2; ++mi)
#pragma unroll
        for (int ni = 0; ni < 2; ++ni) {
          acc0[mi][ni] = __builtin_amdgcn_mfma_f32_32x32x16_f16(ah[mi], bh[ni], acc0[mi][ni], 0, 0, 0);
          acc1[mi][ni] = __builtin_amdgcn_mfma_f32_32x32x16_f16(ah[mi], bl[ni], acc1[mi][ni], 0, 0, 0);
          acc1[mi][ni] = __builtin_amdgcn_mfma_f32_32x32x16_f16(al[mi], bh[ni], acc1[mi][ni], 0, 0, 0);
        }
    }
    __syncthreads();
  }
  // ---- epilogue: D[row][col], col=lane&31, row=(r&3)+8*(r>>2)+4*(lane>>5) ----
  const int col = lane & 31, rhi = lane >> 5;
  float* outp = Pt + (size_t)blockIdx.z * ((size_t)M * D_N);
#pragma unroll
  for (int mi = 0; mi < 2; ++mi)
#pragma unroll
    for (int ni = 0; ni < 2; ++ni)
#pragma unroll
      for (int r = 0; r < 16; ++r) {
        const int m = m0 + (wm * 2 + mi) * 32 + ((r & 3) + 8 * (r >> 2) + 4 * rhi);
        const int n = n0 + (wn * 2 + ni) * 32 + col;
        if (m < M) outp[(size_t)m * D_N + n] = acc0[mi][ni][r] + acc1[mi][ni][r] * LO_INV;
      }
}

// ---------------- reduce split-K + bias + relu (+ optional f16 hi/lo out) ----------------
__global__ __launch_bounds__(256) void reduce_bias_relu(
    const float* __restrict__ Pt, const float* __restrict__ bias,
    float* __restrict__ out_f32, _Float16* __restrict__ out_hi, _Float16* __restrict__ out_lo,
    int MN, int KS)
{
  int i = blockIdx.x * 256 + threadIdx.x;
  if (i >= MN) return;
  float s = 0.0f;
  for (int k = 0; k < KS; ++k) s += Pt[(size_t)k * MN + i];
  s += bias[i & (D_N - 1)];
  s = fmaxf(s, 0.0f);
  if (out_f32) out_f32[i] = s;
  if (out_hi) {
    _Float16 h, l; split16(s, h, l);
    out_hi[i] = h; out_lo[i] = l;
  }
}

// ---------------- head: cls+reg dots, softmax, decode, clip, validity ----------------
__global__ __launch_bounds__(128) void head_kernel(const float* __restrict__ h7,
                                                   const float* __restrict__ cls_w,
                                                   const float* __restrict__ cls_b,
                                                   const float* __restrict__ reg_w,
                                                   const float* __restrict__ reg_b,
                                                   const float* __restrict__ props,
                                                   float* __restrict__ cboxes,
                                                   float* __restrict__ cscores,
                                                   int* __restrict__ cvalid) {
  const int p = blockIdx.x;
  __shared__ float h[D_N];
  __shared__ float outv[105];
  __shared__ float sm[NCLS];
  const int tid = threadIdx.x;
  for (int k = tid; k < D_N; k += 128) h[k] = h7[(size_t)p * D_N + k];
  __syncthreads();

  const int wv = tid >> 6, lane = tid & 63;
  for (int o = wv; o < 105; o += 2) {
    const float* wr = (o < NCLS) ? &cls_w[(size_t)o * D_N] : &reg_w[(size_t)(o - NCLS) * D_N];
    float s = 0.0f;
    for (int k = lane; k < D_N; k += 64) s += h[k] * wr[k];
#pragma unroll
    for (int off = 32; off > 0; off >>= 1) s += __shfl_down(s, off);
    if (lane == 0) outv[o] = s + ((o < NCLS) ? cls_b[o] : reg_b[o - NCLS]);
  }
  __syncthreads();

  if (tid == 0) {
    float mx = outv[0];
    for (int c2 = 1; c2 < NCLS; ++c2) mx = fmaxf(mx, outv[c2]);
    float sum = 0.0f;
    for (int c2 = 0; c2 < NCLS; ++c2) { float e = expf(outv[c2] - mx); sm[c2] = e; sum += e; }
    float inv = 1.0f / sum;
    for (int c2 = 0; c2 < NCLS; ++c2) sm[c2] *= inv;
  }
  __syncthreads();

  if (tid < 20) {
    const int c = tid + 1;
    const float x0 = props[p*4+0], y0 = props[p*4+1], x1 = props[p*4+2], y1 = props[p*4+3];
    const float w = x1 - x0, hh = y1 - y0;
    const float cx = x0 + 0.5f * w, cy = y0 + 0.5f * hh;
    const float dx = outv[NCLS + c*4 + 0];
    const float dy = outv[NCLS + c*4 + 1];
    const float dw = fminf(outv[NCLS + c*4 + 2], BBOX_CLIP_F);
    const float dh = fminf(outv[NCLS + c*4 + 3], BBOX_CLIP_F);
    const float pcx = dx * w + cx, pcy = dy * hh + cy;
    const float pw = expf(dw) * w, ph = expf(dh) * hh;
    float bx0 = pcx - 0.5f * pw, by0 = pcy - 0.5f * ph;
    float bx1 = pcx + 0.5f * pw, by1 = pcy + 0.5f * ph;
    bx0 = fminf(fmaxf(bx0, 0.0f), W_IMG);
    by0 = fminf(fmaxf(by0, 0.0f), H_IMG);
    bx1 = fminf(fmaxf(bx1, 0.0f), W_IMG);
    by1 = fminf(fmaxf(by1, 0.0f), H_IMG);
    const int idx = p * 20 + tid;
    cboxes[idx*4+0] = bx0; cboxes[idx*4+1] = by0;
    cboxes[idx*4+2] = bx1; cboxes[idx*4+3] = by1;
    const float sc = sm[c];
    const bool valid = (sc > 0.05f) && ((bx1 - bx0) >= 1.0f) && ((by1 - by0) >= 1.0f);
    cscores[idx] = sc;
    cvalid[idx] = valid ? 1 : 0;
  }
}

// ---------------- compact valid candidates (order-independent: key embeds idx) ----------------
__global__ void zero_counter(int* c) { if (threadIdx.x == 0 && blockIdx.x == 0) *c = 0; }

__global__ __launch_bounds__(256) void compact_kernel(const float* __restrict__ cscores,
                                                      const int* __restrict__ cvalid,
                                                      unsigned long long* __restrict__ ckeys,
                                                      int* __restrict__ vcount) {
  int i = blockIdx.x * 256 + threadIdx.x;
  if (i >= NCAND) return;
  if (cvalid[i]) {
    int pos = atomicAdd(vcount, 1);
    unsigned u = __float_as_uint(cscores[i]);            // all scores > 0
    ckeys[pos] = ((unsigned long long)(~u) << 32) | (unsigned)i;  // desc score, asc idx
  }
}

// ---------------- bitonic sort over next-pow2(V) + gather sorted candidate arrays ----------------
__global__ __launch_bounds__(1024) void sort_gather(const unsigned long long* __restrict__ ckeys,
                                                    const int* __restrict__ vcount,
                                                    const float* __restrict__ cboxes,
                                                    float4* __restrict__ sbox,
                                                    float* __restrict__ sscore,
                                                    int* __restrict__ slab) {
  __shared__ unsigned long long keys[8192];
  const int tid = threadIdx.x;
  const int V = *vcount;
  int Npad = 64; while (Npad < V) Npad <<= 1;   // V <= 6000 -> <= 8192
  for (int i = tid; i < Npad; i += 1024)
    keys[i] = (i < V) ? ckeys[i] : ~0ULL;
  __syncthreads();
  for (int kk = 2; kk <= Npad; kk <<= 1) {
    for (int j = kk >> 1; j > 0; j >>= 1) {
      for (int i = tid; i < Npad; i += 1024) {
        int ij = i ^ j;
        if (ij > i) {
          unsigned long long a = keys[i], b = keys[ij];
          bool up = ((i & kk) == 0);
          if ((a > b) == up) { keys[i] = b; keys[ij] = a; }
        }
      }
      __syncthreads();
    }
  }
  for (int i = tid; i < V; i += 1024) {
    unsigned long long key = keys[i];
    int idx = (int)(key & 0xffffffffu);
    sbox[i]   = *reinterpret_cast<const float4*>(&cboxes[(size_t)idx * 4]);
    sscore[i] = __uint_as_float(~(unsigned)(key >> 32));
    slab[i]   = idx % 20;
  }
}

// ---------------- greedy NMS, streamed in 64-candidate chunks ----------------
__global__ __launch_bounds__(64) void nms_kernel(const float4* __restrict__ sbox,
                                                 const float* __restrict__ sscore,
                                                 const int* __restrict__ slab,
                                                 const int* __restrict__ vcount,
                                                 float* __restrict__ out) {
  __shared__ float4 kb[100];
  __shared__ int    kl[100];
  __shared__ float4 cb[64];
  __shared__ float  cs[64];
  __shared__ int    cl[64];
  const int lane = threadIdx.x;
  const int V = min(*vcount, NCAND);
  int nk = 0;
  for (int base = 0; base < V && nk < 100; base += 64) {
    const int i = base + lane;
    if (i < V) { cb[lane] = sbox[i]; cs[lane] = sscore[i]; cl[lane] = slab[i]; }
    __syncthreads();
    const int lim = min(64, V - base);
    for (int t = 0; t < lim; ++t) {
      if (nk >= 100) break;
      const float4 bb = cb[t];
      const int lab = cl[t];
      const float ai = (bb.z - bb.x) * (bb.w - bb.y);
      bool sup = false;
      for (int j = lane; j < nk; j += 64) {
        if (kl[j] == lab) {
          const float4 kx = kb[j];
          const float iw = fminf(kx.z, bb.z) - fmaxf(kx.x, bb.x);
          const float ih = fminf(kx.w, bb.w) - fmaxf(kx.y, bb.y);
          const float inter = fmaxf(iw, 0.0f) * fmaxf(ih, 0.0f);
          const float aj = (kx.z - kx.x) * (kx.w - kx.y);
          if (inter / (ai + aj - inter) > 0.5f) sup = true;
        }
      }
      if (!__any(sup)) {
        if (lane == 0) {
          kb[nk] = bb; kl[nk] = lab;
          out[nk*4+0] = bb.x; out[nk*4+1] = bb.y; out[nk*4+2] = bb.z; out[nk*4+3] = bb.w;
          out[400 + nk] = (float)lab;
          out[500 + nk] = cs[t];
        }
        nk++;
        __syncthreads();
      }
    }
    __syncthreads();
  }
  for (int r = nk + lane; r < 100; r += 64) {
    out[r*4+0] = 0.0f; out[r*4+1] = 0.0f; out[r*4+2] = 0.0f; out[r*4+3] = 0.0f;
    out[400 + r] = -1.0f;
    out[500 + r] = 0.0f;
  }
}

// ---------------- launch ----------------
extern "C" void kernel_launch(void* const* d_in, const int* in_sizes, int n_in,
                              void* d_out, int out_size, void* d_ws, size_t ws_size,
                              hipStream_t stream) {
  const float* feat   = (const float*)d_in[1];
  const float* props  = (const float*)d_in[2];
  const float* fc6_w  = (const float*)d_in[3];
  const float* fc6_b  = (const float*)d_in[4];
  const float* fc7_w  = (const float*)d_in[5];
  const float* fc7_b  = (const float*)d_in[6];
  const float* cls_w  = (const float*)d_in[7];
  const float* cls_b  = (const float*)d_in[8];
  const float* reg_w  = (const float*)d_in[9];
  const float* reg_b  = (const float*)d_in[10];

  char* ws = (char*)d_ws;
  size_t off = 0;
  auto alloc = [&](size_t bytes) -> void* {
    void* p = ws + off;
    off += (bytes + 255) & ~(size_t)255;
    return p;
  };

  _Float16* Xhi  = (_Float16*)alloc((size_t)P_N * FIN * 2);      // 15.05 MB
  _Float16* Xlo  = (_Float16*)alloc((size_t)P_N * FIN * 2);      // 15.05 MB
  float*    Pt   = (float*)alloc((size_t)KS6 * P_N * D_N * 4);   // 25.8 MB (ft aliases into here)
  _Float16* h6hi = (_Float16*)alloc((size_t)P_N * D_N * 2);
  _Float16* h6lo = (_Float16*)alloc((size_t)P_N * D_N * 2);
  float*    h7   = (float*)alloc((size_t)P_N * D_N * 4);
  float*  cboxes = (float*)alloc((size_t)NCAND * 4 * 4);
  float* cscores = (float*)alloc((size_t)NCAND * 4);
  int*    cvalid = (int*)alloc((size_t)NCAND * 4);
  unsigned long long* ckeys = (unsigned long long*)alloc((size_t)NCAND * 8);
  float4*   sbox = (float4*)alloc((size_t)NCAND * 16);
  float*  sscore = (float*)alloc((size_t)NCAND * 4);
  int*      slab = (int*)alloc((size_t)NCAND * 4);
  int*    vcount = (int*)alloc(256);
  // ft (6.9 MB) lives in the Pt region: Pt is first written only after roi_align consumed ft.
  float* ft = Pt;
  (void)ws_size; (void)in_sizes; (void)n_in; (void)out_size;

  // 1) feat (C,HW) -> (HW,C)
  transpose_feat<<<dim3((HW_F + 31) / 32, C_N / 32), dim3(32, 8), 0, stream>>>(feat, ft);
  // 2) ROI align -> X hi/lo f16
  roi_align_k<<<dim3(P_N, 49), 256, 0, stream>>>(ft, props, Xhi, Xlo);
  // 3) fc6: MFMA f16 3-pass split-K
  gemm_f16_3p<<<dim3(3, 8, KS6), 256, 0, stream>>>(Xhi, Xlo, fc6_w, Pt, P_N, FIN, STEPS6_PER_Z);
  reduce_bias_relu<<<(P_N * D_N + 255) / 256, 256, 0, stream>>>(
      Pt, fc6_b, nullptr, h6hi, h6lo, P_N * D_N, KS6);
  // 4) fc7
  gemm_f16_3p<<<dim3(3, 8, KS7), 256, 0, stream>>>(h6hi, h6lo, fc7_w, Pt, P_N, D_N, STEPS7_PER_Z);
  reduce_bias_relu<<<(P_N * D_N + 255) / 256, 256, 0, stream>>>(
      Pt, fc7_b, h7, nullptr, nullptr, P_N * D_N, KS7);
  // 5) heads + softmax + decode
  head_kernel<<<P_N, 128, 0, stream>>>(h7, cls_w, cls_b, reg_w, reg_b, props,
                                       cboxes, cscores, cvalid);
  // 6) compact -> sort -> gather
  zero_counter<<<1, 1, 0, stream>>>(vcount);
  compact_kernel<<<(NCAND + 255) / 256, 256, 0, stream>>>(cscores, cvalid, ckeys, vcount);
  sort_gather<<<1, 1024, 0, stream>>>(ckeys, vcount, cboxes, sbox, sscore, slab);
  // 7) NMS + output (400 box floats, 100 labels, 100 scores)
  nms_kernel<<<1, 64, 0, stream>>>(sbox, sscore, slab, vcount, (float*)d_out);
}

// Round 3
// 455.951 us; speedup vs baseline: 1.9798x; 1.4626x over previous
//
#include <hip/hip_runtime.h>
#include <hip/hip_bf16.h>
#include <math.h>

// ---------------- problem constants ----------------
#define P_N   300
#define C_N   512
#define H_F   50
#define W_F   67
#define HW_F  3350
#define D_N   1024
#define FIN   25088
#define NCLS  21
#define NCAND 6000
#define W_IMG 1072.0f
#define H_IMG 800.0f
#define BBOX_CLIP_F 4.135166556742356f
#define KS6   21
#define STEPS6_PER_Z 38
#define KS7   4
#define STEPS7_PER_Z 8
#define KSH   4
#define STEPSH_PER_Z 8
#define NHEAD 128
#define LO_SCALE 2048.0f
#define LO_INV   (1.0f/2048.0f)

typedef __attribute__((ext_vector_type(8)))  _Float16 half8;
typedef __attribute__((ext_vector_type(16))) float    f32x16;

__device__ __forceinline__ void split16(float f, _Float16& h, _Float16& l) {
  h = (_Float16)f;
  l = (_Float16)((f - (float)h) * LO_SCALE);
}

// ---------------- feat (C,H,W) -> (H*W, C) transpose ----------------
__global__ __launch_bounds__(256) void transpose_feat(const float* __restrict__ feat,
                                                      float* __restrict__ ft) {
  __shared__ float tile[32][33];
  const int s0 = blockIdx.x * 32, c0 = blockIdx.y * 32;
  const int tx = threadIdx.x, ty = threadIdx.y;
  for (int r = ty; r < 32; r += 8) {
    int c = c0 + r, s = s0 + tx;
    tile[r][tx] = (s < HW_F) ? feat[(size_t)c * HW_F + s] : 0.0f;
  }
  __syncthreads();
  for (int r = ty; r < 32; r += 8) {
    int s = s0 + r, c = c0 + tx;
    if (s < HW_F) ft[(size_t)s * C_N + c] = tile[tx][r];
  }
}

// ---------------- ROI align -> X as f16 hi/lo, layout [p][c*49+cell] ----------------
__global__ __launch_bounds__(256) void roi_align_k(const float* __restrict__ ft,
                                                   const float* __restrict__ rois,
                                                   _Float16* __restrict__ Xhi,
                                                   _Float16* __restrict__ Xlo) {
  const int p = blockIdx.x;
  const int cell = blockIdx.y;
  const int py = cell / 7, px = cell % 7;
  const float rx0 = rois[p*4+0], ry0 = rois[p*4+1], rx1 = rois[p*4+2], ry1 = rois[p*4+3];
  const float x0r = rx0 * 0.0625f - 0.5f;
  const float y0r = ry0 * 0.0625f - 0.5f;
  const float bw  = (rx1 - rx0) * 0.0625f * (1.0f / 7.0f);
  const float bh  = (ry1 - ry0) * 0.0625f * (1.0f / 7.0f);

  int   yl[2], yh[2], xl[2], xh[2];
  float ly[2], hy[2], lx[2], hx[2];
  bool  vy[2], vx[2];
#pragma unroll
  for (int s = 0; s < 2; ++s) {
    float t  = ((float)(2*py + s) + 0.5f) * 0.5f;
    float ys = y0r + bh * t;
    vy[s] = (ys >= -1.0f) && (ys <= (float)H_F);
    float y = fminf(fmaxf(ys, 0.0f), (float)(H_F - 1));
    int yi = (int)floorf(y);
    yl[s] = yi; yh[s] = min(yi + 1, H_F - 1);
    ly[s] = y - (float)yi; hy[s] = 1.0f - ly[s];

    float t2 = ((float)(2*px + s) + 0.5f) * 0.5f;
    float xs = x0r + bw * t2;
    vx[s] = (xs >= -1.0f) && (xs <= (float)W_F);
    float x = fminf(fmaxf(xs, 0.0f), (float)(W_F - 1));
    int xi = (int)floorf(x);
    xl[s] = xi; xh[s] = min(xi + 1, W_F - 1);
    lx[s] = x - (float)xi; hx[s] = 1.0f - lx[s];
  }

  const int c = threadIdx.x;
  float acc0 = 0.0f, acc1 = 0.0f;
#pragma unroll
  for (int sy = 0; sy < 2; ++sy) {
#pragma unroll
    for (int sx = 0; sx < 2; ++sx) {
      if (vy[sy] && vx[sx]) {
        const float w00 = hy[sy]*hx[sx], w01 = hy[sy]*lx[sx];
        const float w10 = ly[sy]*hx[sx], w11 = ly[sy]*lx[sx];
        const float* p00 = ft + (size_t)(yl[sy]*W_F + xl[sx]) * C_N;
        const float* p01 = ft + (size_t)(yl[sy]*W_F + xh[sx]) * C_N;
        const float* p10 = ft + (size_t)(yh[sy]*W_F + xl[sx]) * C_N;
        const float* p11 = ft + (size_t)(yh[sy]*W_F + xh[sx]) * C_N;
        acc0 += w00*p00[c]     + w01*p01[c]     + w10*p10[c]     + w11*p11[c];
        acc1 += w00*p00[c+256] + w01*p01[c+256] + w10*p10[c+256] + w11*p11[c+256];
      }
    }
  }
  float v0 = acc0 * 0.25f, v1 = acc1 * 0.25f;
  _Float16 h, l;
  size_t i0 = (size_t)p*FIN + (size_t)c*49 + cell;
  size_t i1 = (size_t)p*FIN + (size_t)(c+256)*49 + cell;
  split16(v0, h, l); Xhi[i0] = h; Xlo[i0] = l;
  split16(v1, h, l); Xhi[i1] = h; Xlo[i1] = l;
}

// ---------------- MFMA f16 3-pass split-K GEMM: out = A(M,K) * W(N,K)^T ----------------
__device__ __forceinline__ int swz(int slot, int ks) {
  return slot ^ ((slot >> 5) & 1) ^ (((slot >> 3) & 1) << 1) ^ ((ks & 1) << 2);
}

__global__ __launch_bounds__(256, 2) void gemm_f16_3p(
    const _Float16* __restrict__ Ahi, const _Float16* __restrict__ Alo,
    const float* __restrict__ Wt, float* __restrict__ Pt,
    int M, int K, int steps_per_z, int ldc)
{
  __shared__ _Float16 lds[16384];  // 32KB: A hi[0..4095] lo[4096..8191], B hi[8192..] lo[12288..]
  const int tid  = threadIdx.x;
  const int lane = tid & 63, wave = tid >> 6;
  const int wm = wave >> 1, wn = wave & 1;
  const int m0 = blockIdx.x * 128, n0 = blockIdx.y * 128;
  const int steps_total = K >> 5;
  const int s0 = blockIdx.z * steps_per_z;
  const int s1 = min(s0 + steps_per_z, steps_total);

  f32x16 acc0[2][2], acc1[2][2];
#pragma unroll
  for (int a = 0; a < 2; ++a)
#pragma unroll
    for (int b = 0; b < 2; ++b) {
#pragma unroll
      for (int r = 0; r < 16; ++r) { acc0[a][b][r] = 0.f; acc1[a][b][r] = 0.f; }
    }

  const int srow = tid >> 2;
  const int j8   = tid & 3;
  const int ksW  = j8 >> 1, kc8 = j8 & 1;
  const int wslot = swz((kc8 << 5) | (srow & 31), ksW);

  for (int step = s0; step < s1; ++step) {
    const int kb = step << 5;
#pragma unroll
    for (int half = 0; half < 2; ++half) {
      const int row = srow + half * 64;
      const int mf  = row >> 5;
      const int gm  = m0 + row;
      uint4 vh = make_uint4(0,0,0,0), vl = make_uint4(0,0,0,0);
      if (gm < M) {
        vh = *reinterpret_cast<const uint4*>(Ahi + (size_t)gm * K + kb + j8 * 8);
        vl = *reinterpret_cast<const uint4*>(Alo + (size_t)gm * K + kb + j8 * 8);
      }
      const int base = (mf * 2 + ksW) * 512 + wslot * 8;
      *reinterpret_cast<uint4*>(&lds[base])        = vh;
      *reinterpret_cast<uint4*>(&lds[4096 + base]) = vl;
    }
#pragma unroll
    for (int half = 0; half < 2; ++half) {
      const int n = srow + half * 64;
      const float* wp = Wt + (size_t)(n0 + n) * K + kb + j8 * 8;
      const float4 f0 = *reinterpret_cast<const float4*>(wp);
      const float4 f1 = *reinterpret_cast<const float4*>(wp + 4);
      float fv[8] = {f0.x, f0.y, f0.z, f0.w, f1.x, f1.y, f1.z, f1.w};
      union { _Float16 h[8]; uint4 v; } uh, ul;
#pragma unroll
      for (int e = 0; e < 8; ++e) split16(fv[e], uh.h[e], ul.h[e]);
      const int nf = n >> 5;
      const int base = 8192 + (nf * 2 + ksW) * 512 + wslot * 8;
      *reinterpret_cast<uint4*>(&lds[base])        = uh.v;
      *reinterpret_cast<uint4*>(&lds[4096 + base]) = ul.v;
    }
    __syncthreads();
#pragma unroll
    for (int ks = 0; ks < 2; ++ks) {
      const int rslot = swz(lane, ks) * 8;
      half8 ah[2], al[2], bh[2], bl[2];
#pragma unroll
      for (int mi = 0; mi < 2; ++mi) {
        const int mf = wm * 2 + mi;
        ah[mi] = *reinterpret_cast<const half8*>(&lds[(mf * 2 + ks) * 512 + rslot]);
        al[mi] = *reinterpret_cast<const half8*>(&lds[4096 + (mf * 2 + ks) * 512 + rslot]);
      }
#pragma unroll
      for (int ni = 0; ni < 2; ++ni) {
        const int nf = wn * 2 + ni;
        bh[ni] = *reinterpret_cast<const half8*>(&lds[8192  + (nf * 2 + ks) * 512 + rslot]);
        bl[ni] = *reinterpret_cast<const half8*>(&lds[12288 + (nf * 2 + ks) * 512 + rslot]);
      }
#pragma unroll
      for (int mi = 0; mi < 2; ++mi)
#pragma unroll
        for (int ni = 0; ni < 2; ++ni) {
          acc0[mi][ni] = __builtin_amdgcn_mfma_f32_32x32x16_f16(ah[mi], bh[ni], acc0[mi][ni], 0, 0, 0);
          acc1[mi][ni] = __builtin_amdgcn_mfma_f32_32x32x16_f16(ah[mi], bl[ni], acc1[mi][ni], 0, 0, 0);
          acc1[mi][ni] = __builtin_amdgcn_mfma_f32_32x32x16_f16(al[mi], bh[ni], acc1[mi][ni], 0, 0, 0);
        }
    }
    __syncthreads();
  }
  const int col = lane & 31, rhi = lane >> 5;
  float* outp = Pt + (size_t)blockIdx.z * ((size_t)M * ldc);
#pragma unroll
  for (int mi = 0; mi < 2; ++mi)
#pragma unroll
    for (int ni = 0; ni < 2; ++ni) {
      const int n = n0 + (wn * 2 + ni) * 32 + col;
      if (n >= ldc) continue;
#pragma unroll
      for (int r = 0; r < 16; ++r) {
        const int m = m0 + (wm * 2 + mi) * 32 + ((r & 3) + 8 * (r >> 2) + 4 * rhi);
        if (m < M) outp[(size_t)m * ldc + n] = acc0[mi][ni][r] + acc1[mi][ni][r] * LO_INV;
      }
    }
}

// ---------------- reduce split-K + bias (+relu) -> f32 and/or f16 hi/lo ----------------
__global__ __launch_bounds__(256) void reduce_bias(
    const float* __restrict__ Pt, const float* __restrict__ bias,
    float* __restrict__ out_f32, _Float16* __restrict__ out_hi, _Float16* __restrict__ out_lo,
    int MN, int KS, int nmask, int relu)
{
  int i = blockIdx.x * 256 + threadIdx.x;
  if (i >= MN) return;
  float s = 0.0f;
  for (int k = 0; k < KS; ++k) s += Pt[(size_t)k * MN + i];
  s += bias[i & nmask];
  if (relu) s = fmaxf(s, 0.0f);
  if (out_f32) out_f32[i] = s;
  if (out_hi) {
    _Float16 h, l; split16(s, h, l);
    out_hi[i] = h; out_lo[i] = l;
  }
}

// ---------------- pad [cls_w; reg_w; 0] into Wpad[128][1024], bias likewise ----------------
__global__ __launch_bounds__(256) void prep_head(const float* __restrict__ cls_w,
                                                 const float* __restrict__ cls_b,
                                                 const float* __restrict__ reg_w,
                                                 const float* __restrict__ reg_b,
                                                 float* __restrict__ Wpad,
                                                 float* __restrict__ bpad) {
  const int row = blockIdx.x;
  const int t = threadIdx.x;
  const float* src = (row < NCLS) ? (cls_w + (size_t)row * D_N)
                   : (row < 105)  ? (reg_w + (size_t)(row - NCLS) * D_N) : nullptr;
  float4 v = make_float4(0.f, 0.f, 0.f, 0.f);
  if (src) v = reinterpret_cast<const float4*>(src)[t];
  reinterpret_cast<float4*>(Wpad + (size_t)row * D_N)[t] = v;
  if (t == 0)
    bpad[row] = (row < NCLS) ? cls_b[row] : (row < 105) ? reg_b[row - NCLS] : 0.0f;
}

// ---------------- decode: softmax over 21 logits + box decode + validity (1 wave / proposal) ----
__global__ __launch_bounds__(64) void decode_kernel(const float* __restrict__ logits,
                                                    const float* __restrict__ props,
                                                    float* __restrict__ cboxes,
                                                    float* __restrict__ cscores,
                                                    int* __restrict__ cvalid) {
  const int p = blockIdx.x;
  const int lane = threadIdx.x;
  const float* lg = logits + (size_t)p * NHEAD;

  float s = (lane < NCLS) ? lg[lane] : -__builtin_inff();
  float mx = s;
#pragma unroll
  for (int off = 32; off > 0; off >>= 1) mx = fmaxf(mx, __shfl_xor(mx, off));
  float e = (lane < NCLS) ? expf(s - mx) : 0.0f;
  float sum = e;
#pragma unroll
  for (int off = 32; off > 0; off >>= 1) sum += __shfl_xor(sum, off);
  const float sm = e / sum;

  if (lane >= 1 && lane < NCLS) {
    const int c = lane;
    const float x0 = props[p*4+0], y0 = props[p*4+1], x1 = props[p*4+2], y1 = props[p*4+3];
    const float w = x1 - x0, hh = y1 - y0;
    const float cx = x0 + 0.5f * w, cy = y0 + 0.5f * hh;
    const float dx = lg[NCLS + c*4 + 0];
    const float dy = lg[NCLS + c*4 + 1];
    const float dw = fminf(lg[NCLS + c*4 + 2], BBOX_CLIP_F);
    const float dh = fminf(lg[NCLS + c*4 + 3], BBOX_CLIP_F);
    const float pcx = dx * w + cx, pcy = dy * hh + cy;
    const float pw = expf(dw) * w, ph = expf(dh) * hh;
    float bx0 = pcx - 0.5f * pw, by0 = pcy - 0.5f * ph;
    float bx1 = pcx + 0.5f * pw, by1 = pcy + 0.5f * ph;
    bx0 = fminf(fmaxf(bx0, 0.0f), W_IMG);
    by0 = fminf(fmaxf(by0, 0.0f), H_IMG);
    bx1 = fminf(fmaxf(bx1, 0.0f), W_IMG);
    by1 = fminf(fmaxf(by1, 0.0f), H_IMG);
    const int idx = p * 20 + (c - 1);
    cboxes[idx*4+0] = bx0; cboxes[idx*4+1] = by0;
    cboxes[idx*4+2] = bx1; cboxes[idx*4+3] = by1;
    const bool valid = (sm > 0.05f) && ((bx1 - bx0) >= 1.0f) && ((by1 - by0) >= 1.0f);
    cscores[idx] = sm;
    cvalid[idx] = valid ? 1 : 0;
  }
}

// ---------------- compact valid candidates (order-independent: key embeds idx) ----------------
__global__ void zero_counter(int* c) { if (threadIdx.x == 0 && blockIdx.x == 0) *c = 0; }

__global__ __launch_bounds__(256) void compact_kernel(const float* __restrict__ cscores,
                                                      const int* __restrict__ cvalid,
                                                      unsigned long long* __restrict__ ckeys,
                                                      int* __restrict__ vcount) {
  int i = blockIdx.x * 256 + threadIdx.x;
  if (i >= NCAND) return;
  if (cvalid[i]) {
    int pos = atomicAdd(vcount, 1);
    unsigned u = __float_as_uint(cscores[i]);
    ckeys[pos] = ((unsigned long long)(~u) << 32) | (unsigned)i;
  }
}

// ---------------- bitonic sort over next-pow2(V) + gather sorted candidate arrays ----------------
__global__ __launch_bounds__(1024) void sort_gather(const unsigned long long* __restrict__ ckeys,
                                                    const int* __restrict__ vcount,
                                                    const float* __restrict__ cboxes,
                                                    float4* __restrict__ sbox,
                                                    float* __restrict__ sscore,
                                                    int* __restrict__ slab) {
  __shared__ unsigned long long keys[8192];
  const int tid = threadIdx.x;
  const int V = *vcount;
  int Npad = 64; while (Npad < V) Npad <<= 1;
  for (int i = tid; i < Npad; i += 1024)
    keys[i] = (i < V) ? ckeys[i] : ~0ULL;
  __syncthreads();
  for (int kk = 2; kk <= Npad; kk <<= 1) {
    for (int j = kk >> 1; j > 0; j >>= 1) {
      for (int i = tid; i < Npad; i += 1024) {
        int ij = i ^ j;
        if (ij > i) {
          unsigned long long a = keys[i], b = keys[ij];
          bool up = ((i & kk) == 0);
          if ((a > b) == up) { keys[i] = b; keys[ij] = a; }
        }
      }
      __syncthreads();
    }
  }
  for (int i = tid; i < V; i += 1024) {
    unsigned long long key = keys[i];
    int idx = (int)(key & 0xffffffffu);
    sbox[i]   = *reinterpret_cast<const float4*>(&cboxes[(size_t)idx * 4]);
    sscore[i] = __uint_as_float(~(unsigned)(key >> 32));
    slab[i]   = idx % 20;
  }
}

// ---------------- greedy NMS, streamed in 64-candidate chunks ----------------
__global__ __launch_bounds__(64) void nms_kernel(const float4* __restrict__ sbox,
                                                 const float* __restrict__ sscore,
                                                 const int* __restrict__ slab,
                                                 const int* __restrict__ vcount,
                                                 float* __restrict__ out) {
  __shared__ float4 kb[100];
  __shared__ int    kl[100];
  __shared__ float4 cb[64];
  __shared__ float  cs[64];
  __shared__ int    cl[64];
  const int lane = threadIdx.x;
  const int V = min(*vcount, NCAND);
  int nk = 0;
  for (int base = 0; base < V && nk < 100; base += 64) {
    const int i = base + lane;
    if (i < V) { cb[lane] = sbox[i]; cs[lane] = sscore[i]; cl[lane] = slab[i]; }
    __syncthreads();
    const int lim = min(64, V - base);
    for (int t = 0; t < lim; ++t) {
      if (nk >= 100) break;
      const float4 bb = cb[t];
      const int lab = cl[t];
      const float ai = (bb.z - bb.x) * (bb.w - bb.y);
      bool sup = false;
      for (int j = lane; j < nk; j += 64) {
        if (kl[j] == lab) {
          const float4 kx = kb[j];
          const float iw = fminf(kx.z, bb.z) - fmaxf(kx.x, bb.x);
          const float ih = fminf(kx.w, bb.w) - fmaxf(kx.y, bb.y);
          const float inter = fmaxf(iw, 0.0f) * fmaxf(ih, 0.0f);
          const float aj = (kx.z - kx.x) * (kx.w - kx.y);
          if (inter / (ai + aj - inter) > 0.5f) sup = true;
        }
      }
      if (!__any(sup)) {
        if (lane == 0) {
          kb[nk] = bb; kl[nk] = lab;
          out[nk*4+0] = bb.x; out[nk*4+1] = bb.y; out[nk*4+2] = bb.z; out[nk*4+3] = bb.w;
          out[400 + nk] = (float)lab;
          out[500 + nk] = cs[t];
        }
        nk++;
        __syncthreads();
      }
    }
    __syncthreads();
  }
  for (int r = nk + lane; r < 100; r += 64) {
    out[r*4+0] = 0.0f; out[r*4+1] = 0.0f; out[r*4+2] = 0.0f; out[r*4+3] = 0.0f;
    out[400 + r] = -1.0f;
    out[500 + r] = 0.0f;
  }
}

// ---------------- launch ----------------
extern "C" void kernel_launch(void* const* d_in, const int* in_sizes, int n_in,
                              void* d_out, int out_size, void* d_ws, size_t ws_size,
                              hipStream_t stream) {
  const float* feat   = (const float*)d_in[1];
  const float* props  = (const float*)d_in[2];
  const float* fc6_w  = (const float*)d_in[3];
  const float* fc6_b  = (const float*)d_in[4];
  const float* fc7_w  = (const float*)d_in[5];
  const float* fc7_b  = (const float*)d_in[6];
  const float* cls_w  = (const float*)d_in[7];
  const float* cls_b  = (const float*)d_in[8];
  const float* reg_w  = (const float*)d_in[9];
  const float* reg_b  = (const float*)d_in[10];

  char* ws = (char*)d_ws;
  size_t off = 0;
  auto alloc = [&](size_t bytes) -> void* {
    void* p = ws + off;
    off += (bytes + 255) & ~(size_t)255;
    return p;
  };

  _Float16* Xhi  = (_Float16*)alloc((size_t)P_N * FIN * 2);
  _Float16* Xlo  = (_Float16*)alloc((size_t)P_N * FIN * 2);
  float*    Pt   = (float*)alloc((size_t)KS6 * P_N * D_N * 4);
  _Float16* h6hi = (_Float16*)alloc((size_t)P_N * D_N * 2);
  _Float16* h6lo = (_Float16*)alloc((size_t)P_N * D_N * 2);
  _Float16* h7hi = (_Float16*)alloc((size_t)P_N * D_N * 2);
  _Float16* h7lo = (_Float16*)alloc((size_t)P_N * D_N * 2);
  float*    Wpad = (float*)alloc((size_t)NHEAD * D_N * 4);
  float*    bpad = (float*)alloc((size_t)NHEAD * 4);
  float*  logits = (float*)alloc((size_t)P_N * NHEAD * 4);
  float*  cboxes = (float*)alloc((size_t)NCAND * 4 * 4);
  float* cscores = (float*)alloc((size_t)NCAND * 4);
  int*    cvalid = (int*)alloc((size_t)NCAND * 4);
  unsigned long long* ckeys = (unsigned long long*)alloc((size_t)NCAND * 8);
  float4*   sbox = (float4*)alloc((size_t)NCAND * 16);
  float*  sscore = (float*)alloc((size_t)NCAND * 4);
  int*      slab = (int*)alloc((size_t)NCAND * 4);
  int*    vcount = (int*)alloc(256);
  // ft (6.9 MB) aliases Pt (25.8 MB): Pt first written after roi_align consumed ft.
  float* ft = Pt;
  (void)ws_size; (void)in_sizes; (void)n_in; (void)out_size;

  // 0) pad head weights/bias
  prep_head<<<NHEAD, 256, 0, stream>>>(cls_w, cls_b, reg_w, reg_b, Wpad, bpad);
  // 1) feat (C,HW) -> (HW,C)
  transpose_feat<<<dim3((HW_F + 31) / 32, C_N / 32), dim3(32, 8), 0, stream>>>(feat, ft);
  // 2) ROI align -> X hi/lo f16
  roi_align_k<<<dim3(P_N, 49), 256, 0, stream>>>(ft, props, Xhi, Xlo);
  // 3) fc6
  gemm_f16_3p<<<dim3(3, 8, KS6), 256, 0, stream>>>(Xhi, Xlo, fc6_w, Pt, P_N, FIN, STEPS6_PER_Z, D_N);
  reduce_bias<<<(P_N * D_N + 255) / 256, 256, 0, stream>>>(
      Pt, fc6_b, nullptr, h6hi, h6lo, P_N * D_N, KS6, D_N - 1, 1);
  // 4) fc7
  gemm_f16_3p<<<dim3(3, 8, KS7), 256, 0, stream>>>(h6hi, h6lo, fc7_w, Pt, P_N, D_N, STEPS7_PER_Z, D_N);
  reduce_bias<<<(P_N * D_N + 255) / 256, 256, 0, stream>>>(
      Pt, fc7_b, nullptr, h7hi, h7lo, P_N * D_N, KS7, D_N - 1, 1);
  // 5) head GEMM (N=128 padded) + logits reduce (no relu)
  gemm_f16_3p<<<dim3(3, 1, KSH), 256, 0, stream>>>(h7hi, h7lo, Wpad, Pt, P_N, D_N, STEPSH_PER_Z, NHEAD);
  reduce_bias<<<(P_N * NHEAD + 255) / 256, 256, 0, stream>>>(
      Pt, bpad, logits, nullptr, nullptr, P_N * NHEAD, KSH, NHEAD - 1, 0);
  // 6) softmax + decode + validity
  decode_kernel<<<P_N, 64, 0, stream>>>(logits, props, cboxes, cscores, cvalid);
  // 7) compact -> sort -> gather
  zero_counter<<<1, 1, 0, stream>>>(vcount);
  compact_kernel<<<(NCAND + 255) / 256, 256, 0, stream>>>(cscores, cvalid, ckeys, vcount);
  sort_gather<<<1, 1024, 0, stream>>>(ckeys, vcount, cboxes, sbox, sscore, slab);
  // 8) NMS + output
  nms_kernel<<<1, 64, 0, stream>>>(sbox, sscore, slab, vcount, (float*)d_out);
}

// Round 4
// 343.561 us; speedup vs baseline: 2.6275x; 1.3271x over previous
//
#include <hip/hip_runtime.h>
#include <hip/hip_bf16.h>
#include <math.h>

// ---------------- problem constants ----------------
#define P_N   300
#define C_N   512
#define H_F   50
#define W_F   67
#define HW_F  3350
#define D_N   1024
#define FIN   25088
#define NCLS  21
#define NCAND 6000
#define W_IMG 1072.0f
#define H_IMG 800.0f
#define BBOX_CLIP_F 4.135166556742356f
#define KS6   21
#define STEPS6_PER_Z 38
#define KS7   4
#define STEPS7_PER_Z 8
#define KSH   4
#define STEPSH_PER_Z 8
#define NHEAD 128
#define LO_SCALE 2048.0f
#define LO_INV   (1.0f/2048.0f)

typedef __attribute__((ext_vector_type(8)))  _Float16 half8;
typedef __attribute__((ext_vector_type(16))) float    f32x16;

__device__ __forceinline__ void split16(float f, _Float16& h, _Float16& l) {
  h = (_Float16)f;
  l = (_Float16)((f - (float)h) * LO_SCALE);
}

// ---------------- feat (C,H,W) -> (H*W, C) transpose ----------------
__global__ __launch_bounds__(256) void transpose_feat(const float* __restrict__ feat,
                                                      float* __restrict__ ft) {
  __shared__ float tile[32][33];
  const int s0 = blockIdx.x * 32, c0 = blockIdx.y * 32;
  const int tx = threadIdx.x, ty = threadIdx.y;
  for (int r = ty; r < 32; r += 8) {
    int c = c0 + r, s = s0 + tx;
    tile[r][tx] = (s < HW_F) ? feat[(size_t)c * HW_F + s] : 0.0f;
  }
  __syncthreads();
  for (int r = ty; r < 32; r += 8) {
    int s = s0 + r, c = c0 + tx;
    if (s < HW_F) ft[(size_t)s * C_N + c] = tile[tx][r];
  }
}

// ---------------- ROI align: block per (proposal, channel-half) ----------------
// Computes val[c][cell] for 256 channels x 49 cells, stages the contiguous
// 25088B chunk of X (layout [p][c*49+cell]) in LDS, writes coalesced uint4.
__global__ __launch_bounds__(256) void roi_align_k(const float* __restrict__ ft,
                                                   const float* __restrict__ rois,
                                                   _Float16* __restrict__ Xhi,
                                                   _Float16* __restrict__ Xlo) {
  __shared__ _Float16 hbuf[12544] __attribute__((aligned(16)));
  __shared__ _Float16 lbuf[12544] __attribute__((aligned(16)));
  __shared__ int   g_yl[14], g_yh[14], g_xl[14], g_xh[14];
  __shared__ float g_ly[14], g_hy[14], g_lx[14], g_hx[14];
  __shared__ int   g_vy[14], g_vx[14];

  const int p   = blockIdx.x;
  const int ch  = blockIdx.y;        // channel half: 0 or 1
  const int tid = threadIdx.x;

  if (tid < 14) {
    const float rx0 = rois[p*4+0], ry0 = rois[p*4+1], rx1 = rois[p*4+2], ry1 = rois[p*4+3];
    const float x0r = rx0 * 0.0625f - 0.5f;
    const float y0r = ry0 * 0.0625f - 0.5f;
    const float bw  = (rx1 - rx0) * 0.0625f * (1.0f / 7.0f);
    const float bh  = (ry1 - ry0) * 0.0625f * (1.0f / 7.0f);
    const float t   = ((float)tid + 0.5f) * 0.5f;

    const float ys = y0r + bh * t;
    g_vy[tid] = (ys >= -1.0f) && (ys <= (float)H_F);
    float y = fminf(fmaxf(ys, 0.0f), (float)(H_F - 1));
    int yi = (int)floorf(y);
    g_yl[tid] = yi; g_yh[tid] = min(yi + 1, H_F - 1);
    g_ly[tid] = y - (float)yi; g_hy[tid] = 1.0f - (y - (float)yi);

    const float xs = x0r + bw * t;
    g_vx[tid] = (xs >= -1.0f) && (xs <= (float)W_F);
    float x = fminf(fmaxf(xs, 0.0f), (float)(W_F - 1));
    int xi = (int)floorf(x);
    g_xl[tid] = xi; g_xh[tid] = min(xi + 1, W_F - 1);
    g_lx[tid] = x - (float)xi; g_hx[tid] = 1.0f - (x - (float)xi);
  }
  __syncthreads();

  const int c = ch * 256 + tid;
  for (int cell = 0; cell < 49; ++cell) {
    const int py = cell / 7;
    const int px = cell - py * 7;
    float acc = 0.0f;
#pragma unroll
    for (int sy = 0; sy < 2; ++sy) {
      const int iy = 2 * py + sy;
      if (!g_vy[iy]) continue;                 // uniform branch
      const float ly = g_ly[iy], hy = g_hy[iy];
      const int ry0i = g_yl[iy] * W_F, ry1i = g_yh[iy] * W_F;
#pragma unroll
      for (int sx = 0; sx < 2; ++sx) {
        const int ix = 2 * px + sx;
        if (!g_vx[ix]) continue;               // uniform branch
        const float lx = g_lx[ix], hx = g_hx[ix];
        const float* b00 = ft + (size_t)(ry0i + g_xl[ix]) * C_N;
        const float* b01 = ft + (size_t)(ry0i + g_xh[ix]) * C_N;
        const float* b10 = ft + (size_t)(ry1i + g_xl[ix]) * C_N;
        const float* b11 = ft + (size_t)(ry1i + g_xh[ix]) * C_N;
        acc += (hy*hx)*b00[c] + (hy*lx)*b01[c] + (ly*hx)*b10[c] + (ly*lx)*b11[c];
      }
    }
    _Float16 h, l;
    split16(acc * 0.25f, h, l);
    hbuf[tid * 49 + cell] = h;
    lbuf[tid * 49 + cell] = l;
  }
  __syncthreads();

  // coalesced copy: 12544 halfs = 1568 uint4 per array
  const size_t base = (size_t)p * FIN + (size_t)ch * 12544;
  const uint4* hs = (const uint4*)hbuf;
  const uint4* ls = (const uint4*)lbuf;
  uint4* dh = (uint4*)(Xhi + base);
  uint4* dl = (uint4*)(Xlo + base);
  for (int k = tid; k < 1568; k += 256) { dh[k] = hs[k]; dl[k] = ls[k]; }
}

// ---------------- MFMA f16 3-pass split-K GEMM: out = A(M,K) * W(N,K)^T ----------------
__device__ __forceinline__ int swz(int slot, int ks) {
  return slot ^ ((slot >> 5) & 1) ^ (((slot >> 3) & 1) << 1) ^ ((ks & 1) << 2);
}

__global__ __launch_bounds__(256, 2) void gemm_f16_3p(
    const _Float16* __restrict__ Ahi, const _Float16* __restrict__ Alo,
    const float* __restrict__ Wt, float* __restrict__ Pt,
    int M, int K, int steps_per_z, int ldc)
{
  __shared__ _Float16 lds[16384];  // 32KB: A hi[0..4095] lo[4096..8191], B hi[8192..] lo[12288..]
  const int tid  = threadIdx.x;
  const int lane = tid & 63, wave = tid >> 6;
  const int wm = wave >> 1, wn = wave & 1;
  const int m0 = blockIdx.x * 128, n0 = blockIdx.y * 128;
  const int steps_total = K >> 5;
  const int s0 = blockIdx.z * steps_per_z;
  const int s1 = min(s0 + steps_per_z, steps_total);

  f32x16 acc0[2][2], acc1[2][2];
#pragma unroll
  for (int a = 0; a < 2; ++a)
#pragma unroll
    for (int b = 0; b < 2; ++b) {
#pragma unroll
      for (int r = 0; r < 16; ++r) { acc0[a][b][r] = 0.f; acc1[a][b][r] = 0.f; }
    }

  const int srow = tid >> 2;
  const int j8   = tid & 3;
  const int ksW  = j8 >> 1, kc8 = j8 & 1;
  const int wslot = swz((kc8 << 5) | (srow & 31), ksW);

  for (int step = s0; step < s1; ++step) {
    const int kb = step << 5;
#pragma unroll
    for (int half = 0; half < 2; ++half) {
      const int row = srow + half * 64;
      const int mf  = row >> 5;
      const int gm  = m0 + row;
      uint4 vh = make_uint4(0,0,0,0), vl = make_uint4(0,0,0,0);
      if (gm < M) {
        vh = *reinterpret_cast<const uint4*>(Ahi + (size_t)gm * K + kb + j8 * 8);
        vl = *reinterpret_cast<const uint4*>(Alo + (size_t)gm * K + kb + j8 * 8);
      }
      const int base = (mf * 2 + ksW) * 512 + wslot * 8;
      *reinterpret_cast<uint4*>(&lds[base])        = vh;
      *reinterpret_cast<uint4*>(&lds[4096 + base]) = vl;
    }
#pragma unroll
    for (int half = 0; half < 2; ++half) {
      const int n = srow + half * 64;
      const float* wp = Wt + (size_t)(n0 + n) * K + kb + j8 * 8;
      const float4 f0 = *reinterpret_cast<const float4*>(wp);
      const float4 f1 = *reinterpret_cast<const float4*>(wp + 4);
      float fv[8] = {f0.x, f0.y, f0.z, f0.w, f1.x, f1.y, f1.z, f1.w};
      union { _Float16 h[8]; uint4 v; } uh, ul;
#pragma unroll
      for (int e = 0; e < 8; ++e) split16(fv[e], uh.h[e], ul.h[e]);
      const int nf = n >> 5;
      const int base = 8192 + (nf * 2 + ksW) * 512 + wslot * 8;
      *reinterpret_cast<uint4*>(&lds[base])        = uh.v;
      *reinterpret_cast<uint4*>(&lds[4096 + base]) = ul.v;
    }
    __syncthreads();
#pragma unroll
    for (int ks = 0; ks < 2; ++ks) {
      const int rslot = swz(lane, ks) * 8;
      half8 ah[2], al[2], bh[2], bl[2];
#pragma unroll
      for (int mi = 0; mi < 2; ++mi) {
        const int mf = wm * 2 + mi;
        ah[mi] = *reinterpret_cast<const half8*>(&lds[(mf * 2 + ks) * 512 + rslot]);
        al[mi] = *reinterpret_cast<const half8*>(&lds[4096 + (mf * 2 + ks) * 512 + rslot]);
      }
#pragma unroll
      for (int ni = 0; ni < 2; ++ni) {
        const int nf = wn * 2 + ni;
        bh[ni] = *reinterpret_cast<const half8*>(&lds[8192  + (nf * 2 + ks) * 512 + rslot]);
        bl[ni] = *reinterpret_cast<const half8*>(&lds[12288 + (nf * 2 + ks) * 512 + rslot]);
      }
#pragma unroll
      for (int mi = 0; mi < 2; ++mi)
#pragma unroll
        for (int ni = 0; ni < 2; ++ni) {
          acc0[mi][ni] = __builtin_amdgcn_mfma_f32_32x32x16_f16(ah[mi], bh[ni], acc0[mi][ni], 0, 0, 0);
          acc1[mi][ni] = __builtin_amdgcn_mfma_f32_32x32x16_f16(ah[mi], bl[ni], acc1[mi][ni], 0, 0, 0);
          acc1[mi][ni] = __builtin_amdgcn_mfma_f32_32x32x16_f16(al[mi], bh[ni], acc1[mi][ni], 0, 0, 0);
        }
    }
    __syncthreads();
  }
  const int col = lane & 31, rhi = lane >> 5;
  float* outp = Pt + (size_t)blockIdx.z * ((size_t)M * ldc);
#pragma unroll
  for (int mi = 0; mi < 2; ++mi)
#pragma unroll
    for (int ni = 0; ni < 2; ++ni) {
      const int n = n0 + (wn * 2 + ni) * 32 + col;
      if (n >= ldc) continue;
#pragma unroll
      for (int r = 0; r < 16; ++r) {
        const int m = m0 + (wm * 2 + mi) * 32 + ((r & 3) + 8 * (r >> 2) + 4 * rhi);
        if (m < M) outp[(size_t)m * ldc + n] = acc0[mi][ni][r] + acc1[mi][ni][r] * LO_INV;
      }
    }
}

// ---------------- reduce split-K + bias (+relu) -> f32 and/or f16 hi/lo ----------------
__global__ __launch_bounds__(256) void reduce_bias(
    const float* __restrict__ Pt, const float* __restrict__ bias,
    float* __restrict__ out_f32, _Float16* __restrict__ out_hi, _Float16* __restrict__ out_lo,
    int MN, int KS, int nmask, int relu)
{
  int i = blockIdx.x * 256 + threadIdx.x;
  if (i >= MN) return;
  float s = 0.0f;
  for (int k = 0; k < KS; ++k) s += Pt[(size_t)k * MN + i];
  s += bias[i & nmask];
  if (relu) s = fmaxf(s, 0.0f);
  if (out_f32) out_f32[i] = s;
  if (out_hi) {
    _Float16 h, l; split16(s, h, l);
    out_hi[i] = h; out_lo[i] = l;
  }
}

// ---------------- pad [cls_w; reg_w; 0] into Wpad[128][1024], bias likewise ----------------
__global__ __launch_bounds__(256) void prep_head(const float* __restrict__ cls_w,
                                                 const float* __restrict__ cls_b,
                                                 const float* __restrict__ reg_w,
                                                 const float* __restrict__ reg_b,
                                                 float* __restrict__ Wpad,
                                                 float* __restrict__ bpad) {
  const int row = blockIdx.x;
  const int t = threadIdx.x;
  const float* src = (row < NCLS) ? (cls_w + (size_t)row * D_N)
                   : (row < 105)  ? (reg_w + (size_t)(row - NCLS) * D_N) : nullptr;
  float4 v = make_float4(0.f, 0.f, 0.f, 0.f);
  if (src) v = reinterpret_cast<const float4*>(src)[t];
  reinterpret_cast<float4*>(Wpad + (size_t)row * D_N)[t] = v;
  if (t == 0)
    bpad[row] = (row < NCLS) ? cls_b[row] : (row < 105) ? reg_b[row - NCLS] : 0.0f;
}

// ---------------- decode: softmax over 21 logits + box decode + validity (1 wave / proposal) ----
__global__ __launch_bounds__(64) void decode_kernel(const float* __restrict__ logits,
                                                    const float* __restrict__ props,
                                                    float* __restrict__ cboxes,
                                                    float* __restrict__ cscores,
                                                    int* __restrict__ cvalid) {
  const int p = blockIdx.x;
  const int lane = threadIdx.x;
  const float* lg = logits + (size_t)p * NHEAD;

  float s = (lane < NCLS) ? lg[lane] : -__builtin_inff();
  float mx = s;
#pragma unroll
  for (int off = 32; off > 0; off >>= 1) mx = fmaxf(mx, __shfl_xor(mx, off));
  float e = (lane < NCLS) ? expf(s - mx) : 0.0f;
  float sum = e;
#pragma unroll
  for (int off = 32; off > 0; off >>= 1) sum += __shfl_xor(sum, off);
  const float sm = e / sum;

  if (lane >= 1 && lane < NCLS) {
    const int c = lane;
    const float x0 = props[p*4+0], y0 = props[p*4+1], x1 = props[p*4+2], y1 = props[p*4+3];
    const float w = x1 - x0, hh = y1 - y0;
    const float cx = x0 + 0.5f * w, cy = y0 + 0.5f * hh;
    const float dx = lg[NCLS + c*4 + 0];
    const float dy = lg[NCLS + c*4 + 1];
    const float dw = fminf(lg[NCLS + c*4 + 2], BBOX_CLIP_F);
    const float dh = fminf(lg[NCLS + c*4 + 3], BBOX_CLIP_F);
    const float pcx = dx * w + cx, pcy = dy * hh + cy;
    const float pw = expf(dw) * w, ph = expf(dh) * hh;
    float bx0 = pcx - 0.5f * pw, by0 = pcy - 0.5f * ph;
    float bx1 = pcx + 0.5f * pw, by1 = pcy + 0.5f * ph;
    bx0 = fminf(fmaxf(bx0, 0.0f), W_IMG);
    by0 = fminf(fmaxf(by0, 0.0f), H_IMG);
    bx1 = fminf(fmaxf(bx1, 0.0f), W_IMG);
    by1 = fminf(fmaxf(by1, 0.0f), H_IMG);
    const int idx = p * 20 + (c - 1);
    cboxes[idx*4+0] = bx0; cboxes[idx*4+1] = by0;
    cboxes[idx*4+2] = bx1; cboxes[idx*4+3] = by1;
    const bool valid = (sm > 0.05f) && ((bx1 - bx0) >= 1.0f) && ((by1 - by0) >= 1.0f);
    cscores[idx] = sm;
    cvalid[idx] = valid ? 1 : 0;
  }
}

// ---------------- compact valid candidates (order-independent: key embeds idx) ----------------
__global__ void zero_counter(int* c) { if (threadIdx.x == 0 && blockIdx.x == 0) *c = 0; }

__global__ __launch_bounds__(256) void compact_kernel(const float* __restrict__ cscores,
                                                      const int* __restrict__ cvalid,
                                                      unsigned long long* __restrict__ ckeys,
                                                      int* __restrict__ vcount) {
  int i = blockIdx.x * 256 + threadIdx.x;
  if (i >= NCAND) return;
  if (cvalid[i]) {
    int pos = atomicAdd(vcount, 1);
    unsigned u = __float_as_uint(cscores[i]);
    ckeys[pos] = ((unsigned long long)(~u) << 32) | (unsigned)i;
  }
}

// ---------------- bitonic sort over next-pow2(V) + gather sorted candidate arrays ----------------
__global__ __launch_bounds__(1024) void sort_gather(const unsigned long long* __restrict__ ckeys,
                                                    const int* __restrict__ vcount,
                                                    const float* __restrict__ cboxes,
                                                    float4* __restrict__ sbox,
                                                    float* __restrict__ sscore,
                                                    int* __restrict__ slab) {
  __shared__ unsigned long long keys[8192];
  const int tid = threadIdx.x;
  const int V = *vcount;
  int Npad = 64; while (Npad < V) Npad <<= 1;
  for (int i = tid; i < Npad; i += 1024)
    keys[i] = (i < V) ? ckeys[i] : ~0ULL;
  __syncthreads();
  for (int kk = 2; kk <= Npad; kk <<= 1) {
    for (int j = kk >> 1; j > 0; j >>= 1) {
      for (int i = tid; i < Npad; i += 1024) {
        int ij = i ^ j;
        if (ij > i) {
          unsigned long long a = keys[i], b = keys[ij];
          bool up = ((i & kk) == 0);
          if ((a > b) == up) { keys[i] = b; keys[ij] = a; }
        }
      }
      __syncthreads();
    }
  }
  for (int i = tid; i < V; i += 1024) {
    unsigned long long key = keys[i];
    int idx = (int)(key & 0xffffffffu);
    sbox[i]   = *reinterpret_cast<const float4*>(&cboxes[(size_t)idx * 4]);
    sscore[i] = __uint_as_float(~(unsigned)(key >> 32));
    slab[i]   = idx % 20;
  }
}

// ---------------- greedy NMS, streamed in 64-candidate chunks ----------------
__global__ __launch_bounds__(64) void nms_kernel(const float4* __restrict__ sbox,
                                                 const float* __restrict__ sscore,
                                                 const int* __restrict__ slab,
                                                 const int* __restrict__ vcount,
                                                 float* __restrict__ out) {
  __shared__ float4 kb[100];
  __shared__ int    kl[100];
  __shared__ float4 cb[64];
  __shared__ float  cs[64];
  __shared__ int    cl[64];
  const int lane = threadIdx.x;
  const int V = min(*vcount, NCAND);
  int nk = 0;
  for (int base = 0; base < V && nk < 100; base += 64) {
    const int i = base + lane;
    if (i < V) { cb[lane] = sbox[i]; cs[lane] = sscore[i]; cl[lane] = slab[i]; }
    __syncthreads();
    const int lim = min(64, V - base);
    for (int t = 0; t < lim; ++t) {
      if (nk >= 100) break;
      const float4 bb = cb[t];
      const int lab = cl[t];
      const float ai = (bb.z - bb.x) * (bb.w - bb.y);
      bool sup = false;
      for (int j = lane; j < nk; j += 64) {
        if (kl[j] == lab) {
          const float4 kx = kb[j];
          const float iw = fminf(kx.z, bb.z) - fmaxf(kx.x, bb.x);
          const float ih = fminf(kx.w, bb.w) - fmaxf(kx.y, bb.y);
          const float inter = fmaxf(iw, 0.0f) * fmaxf(ih, 0.0f);
          const float aj = (kx.z - kx.x) * (kx.w - kx.y);
          if (inter / (ai + aj - inter) > 0.5f) sup = true;
        }
      }
      if (!__any(sup)) {
        if (lane == 0) {
          kb[nk] = bb; kl[nk] = lab;
          out[nk*4+0] = bb.x; out[nk*4+1] = bb.y; out[nk*4+2] = bb.z; out[nk*4+3] = bb.w;
          out[400 + nk] = (float)lab;
          out[500 + nk] = cs[t];
        }
        nk++;
        __syncthreads();
      }
    }
    __syncthreads();
  }
  for (int r = nk + lane; r < 100; r += 64) {
    out[r*4+0] = 0.0f; out[r*4+1] = 0.0f; out[r*4+2] = 0.0f; out[r*4+3] = 0.0f;
    out[400 + r] = -1.0f;
    out[500 + r] = 0.0f;
  }
}

// ---------------- launch ----------------
extern "C" void kernel_launch(void* const* d_in, const int* in_sizes, int n_in,
                              void* d_out, int out_size, void* d_ws, size_t ws_size,
                              hipStream_t stream) {
  const float* feat   = (const float*)d_in[1];
  const float* props  = (const float*)d_in[2];
  const float* fc6_w  = (const float*)d_in[3];
  const float* fc6_b  = (const float*)d_in[4];
  const float* fc7_w  = (const float*)d_in[5];
  const float* fc7_b  = (const float*)d_in[6];
  const float* cls_w  = (const float*)d_in[7];
  const float* cls_b  = (const float*)d_in[8];
  const float* reg_w  = (const float*)d_in[9];
  const float* reg_b  = (const float*)d_in[10];

  char* ws = (char*)d_ws;
  size_t off = 0;
  auto alloc = [&](size_t bytes) -> void* {
    void* p = ws + off;
    off += (bytes + 255) & ~(size_t)255;
    return p;
  };

  _Float16* Xhi  = (_Float16*)alloc((size_t)P_N * FIN * 2);
  _Float16* Xlo  = (_Float16*)alloc((size_t)P_N * FIN * 2);
  float*    Pt   = (float*)alloc((size_t)KS6 * P_N * D_N * 4);
  _Float16* h6hi = (_Float16*)alloc((size_t)P_N * D_N * 2);
  _Float16* h6lo = (_Float16*)alloc((size_t)P_N * D_N * 2);
  _Float16* h7hi = (_Float16*)alloc((size_t)P_N * D_N * 2);
  _Float16* h7lo = (_Float16*)alloc((size_t)P_N * D_N * 2);
  float*    Wpad = (float*)alloc((size_t)NHEAD * D_N * 4);
  float*    bpad = (float*)alloc((size_t)NHEAD * 4);
  float*  logits = (float*)alloc((size_t)P_N * NHEAD * 4);
  float*  cboxes = (float*)alloc((size_t)NCAND * 4 * 4);
  float* cscores = (float*)alloc((size_t)NCAND * 4);
  int*    cvalid = (int*)alloc((size_t)NCAND * 4);
  unsigned long long* ckeys = (unsigned long long*)alloc((size_t)NCAND * 8);
  float4*   sbox = (float4*)alloc((size_t)NCAND * 16);
  float*  sscore = (float*)alloc((size_t)NCAND * 4);
  int*      slab = (int*)alloc((size_t)NCAND * 4);
  int*    vcount = (int*)alloc(256);
  // ft (6.9 MB) aliases Pt (25.8 MB): Pt first written after roi_align consumed ft.
  float* ft = Pt;
  (void)ws_size; (void)in_sizes; (void)n_in; (void)out_size;

  // 0) pad head weights/bias
  prep_head<<<NHEAD, 256, 0, stream>>>(cls_w, cls_b, reg_w, reg_b, Wpad, bpad);
  // 1) feat (C,HW) -> (HW,C)
  transpose_feat<<<dim3((HW_F + 31) / 32, C_N / 32), dim3(32, 8), 0, stream>>>(feat, ft);
  // 2) ROI align -> X hi/lo f16 (block per proposal x channel-half, LDS-staged writes)
  roi_align_k<<<dim3(P_N, 2), 256, 0, stream>>>(ft, props, Xhi, Xlo);
  // 3) fc6
  gemm_f16_3p<<<dim3(3, 8, KS6), 256, 0, stream>>>(Xhi, Xlo, fc6_w, Pt, P_N, FIN, STEPS6_PER_Z, D_N);
  reduce_bias<<<(P_N * D_N + 255) / 256, 256, 0, stream>>>(
      Pt, fc6_b, nullptr, h6hi, h6lo, P_N * D_N, KS6, D_N - 1, 1);
  // 4) fc7
  gemm_f16_3p<<<dim3(3, 8, KS7), 256, 0, stream>>>(h6hi, h6lo, fc7_w, Pt, P_N, D_N, STEPS7_PER_Z, D_N);
  reduce_bias<<<(P_N * D_N + 255) / 256, 256, 0, stream>>>(
      Pt, fc7_b, nullptr, h7hi, h7lo, P_N * D_N, KS7, D_N - 1, 1);
  // 5) head GEMM (N=128 padded) + logits reduce (no relu)
  gemm_f16_3p<<<dim3(3, 1, KSH), 256, 0, stream>>>(h7hi, h7lo, Wpad, Pt, P_N, D_N, STEPSH_PER_Z, NHEAD);
  reduce_bias<<<(P_N * NHEAD + 255) / 256, 256, 0, stream>>>(
      Pt, bpad, logits, nullptr, nullptr, P_N * NHEAD, KSH, NHEAD - 1, 0);
  // 6) softmax + decode + validity
  decode_kernel<<<P_N, 64, 0, stream>>>(logits, props, cboxes, cscores, cvalid);
  // 7) compact -> sort -> gather
  zero_counter<<<1, 1, 0, stream>>>(vcount);
  compact_kernel<<<(NCAND + 255) / 256, 256, 0, stream>>>(cscores, cvalid, ckeys, vcount);
  sort_gather<<<1, 1024, 0, stream>>>(ckeys, vcount, cboxes, sbox, sscore, slab);
  // 8) NMS + output
  nms_kernel<<<1, 64, 0, stream>>>(sbox, sscore, slab, vcount, (float*)d_out);
}